// Round 12
// baseline (187.294 us; speedup 1.0000x reference)
//
#include <hip/hip_runtime.h>

// bf16/f16 MFMA pipeline. E=1024, H=16, HD=64, B=2, N=2048.
// attn: 256-thr blocks own 128 QUERIES x all keys; 4 waves split by query
// (32 q each), each wave processes the full 128-key staged tile (4 u-blocks).
// Grid 512, XCD-clustered (lb%8 = XCD): each XCD owns 4 bh (2MB K/V in L2).
// K GLDS-staged (XOR-swizzled); V GLDS-staged LINEARLY from vfb (LDS image,
// swizzle pre-baked by the qkv epilogue).
// GEMMs: both now use the M=64 x N=128 BK=32 tile (256 thr, 12KB LDS):
//   qkv grid (32,48) = 1536 blocks = 6 blocks/CU (was 768 = 3/CU, occupancy
//   27% and stall-dominated: MfmaUtil 19 / VALUBusy 12). 64-aligned outcol
//   tiles make each qkv block purely Q, K, or V.
// mfma_f32_16x16x32_bf16: A[m=l16][k=quad*8+j] ; B[k=quad*8+j][n=l16]
//                         C/D: D[row=quad*4+reg][col=l16]
// PV uses mfma_f32_16x16x32_f16 (K=32, full rate).

#define SEQ 2048
#define NH  16

typedef __attribute__((ext_vector_type(8))) short short8;
typedef __attribute__((ext_vector_type(4))) short short4v;
typedef __attribute__((ext_vector_type(4))) float floatx4;
typedef __attribute__((ext_vector_type(4))) _Float16 half4;
typedef __attribute__((ext_vector_type(8))) _Float16 half8;
typedef __attribute__((ext_vector_type(2))) _Float16 half2v;
typedef __attribute__((ext_vector_type(2))) __fp16 fp16x2;

// fold 1/sqrt(64) * log2(e) into Q; softmax runs in exp2 domain with m=0
#define QSCALE 0.1803368801111204f

__device__ __forceinline__ short f2bf(float f) {
    union { float f; unsigned u; } v; v.f = f;
    unsigned r = v.u + 0x7fffu + ((v.u >> 16) & 1u);   // RNE
    return (short)(r >> 16);
}

__device__ __forceinline__ float fast_exp2(float x) {
#if __has_builtin(__builtin_amdgcn_exp2f)
    return __builtin_amdgcn_exp2f(x);
#else
    return exp2f(x);
#endif
}

__device__ __forceinline__ half2v cvt_pk(float a, float b) {
#if __has_builtin(__builtin_amdgcn_cvt_pkrtz)
    union { fp16x2 i; half2v o; } u;
    u.i = __builtin_amdgcn_cvt_pkrtz(a, b);
    return u.o;
#else
    half2v r; r.x = (_Float16)a; r.y = (_Float16)b; return r;
#endif
}

#define GLDS16(gp, lp)                                                          \
    __builtin_amdgcn_global_load_lds(                                           \
        (const __attribute__((address_space(1))) unsigned int*)(gp),            \
        (__attribute__((address_space(3))) unsigned int*)(lp), 16, 0, 0)

// ---------------------------------------------------------------------------
// Fused prep: [0,2048) cast x fp32->bf16 ; [2048,2816) transpose W_qkv ;
// [2816,3072) transpose W_out. One launch instead of three.
// ---------------------------------------------------------------------------
__global__ __launch_bounds__(256) void prep_kernel(
    const float* __restrict__ x,  short* __restrict__ xb,
    const float* __restrict__ wq, short* __restrict__ wqkvt,
    const float* __restrict__ wo, short* __restrict__ woutt)
{
    const int tid = threadIdx.x;
    const int b = blockIdx.x;
    if (b < 2048) {
        int i = b * 256 + tid;
        const float4* in4 = (const float4*)x + (size_t)i * 2;
        float4 a = in4[0], c = in4[1];
        short8 o = { f2bf(a.x), f2bf(a.y), f2bf(a.z), f2bf(a.w),
                     f2bf(c.x), f2bf(c.y), f2bf(c.z), f2bf(c.w) };
        *((short8*)xb + i) = o;
        return;
    }
    __shared__ float T[64][65];
    const float* in; short* out; int R, C, c0, r0;
    if (b < 2816) {
        int t = b - 2048; in = wq; out = wqkvt; R = 1024; C = 3072;
        c0 = (t % 48) * 64; r0 = (t / 48) * 64;
    } else {
        int t = b - 2816; in = wo; out = woutt; R = 1024; C = 1024;
        c0 = (t & 15) * 64; r0 = (t >> 4) * 64;
    }
#pragma unroll
    for (int it = 0; it < 4; ++it) {
        int r = it * 16 + (tid >> 4), c = (tid & 15) * 4;
        float4 v = *(const float4*)(in + (size_t)(r0 + r) * C + c0 + c);
        T[c+0][r] = v.x; T[c+1][r] = v.y; T[c+2][r] = v.z; T[c+3][r] = v.w;
    }
    __syncthreads();
#pragma unroll
    for (int it = 0; it < 4; ++it) {
        int oc = it * 16 + (tid >> 4), k = (tid & 15) * 4;
        short4v o = { f2bf(T[oc][k]), f2bf(T[oc][k+1]), f2bf(T[oc][k+2]), f2bf(T[oc][k+3]) };
        *(short4v*)(out + (size_t)(c0 + oc) * R + r0 + k) = o;
    }
}

// ---------------------------------------------------------------------------
// Stage 1: qkv^T = W_qkv^T @ x^T (+b). M=64 outcols x N=128 tokens, BK=32,
// 256 thr, grid (32,48) = 1536 blocks = 6 blocks/CU. Each block is purely
// Q, K, or V (64-aligned outcol tile within 192-sized head sections).
// Q/K: short4v stores per 4 consecutive d. V: scattered 2B stores into the
// attn LDS-image layout (vfb).
// ---------------------------------------------------------------------------
__global__ __launch_bounds__(256) void qkv_gemm_kernel(
    const short* __restrict__ wt, const short* __restrict__ xb,
    const float* __restrict__ bias,
    short* __restrict__ qb, short* __restrict__ kb, _Float16* __restrict__ vfb)
{
    __shared__ short As[64 * 32];     // 4 KB (outcols)
    __shared__ short Bs[128 * 32];    // 8 KB (tokens)
    const int tid  = threadIdx.x;
    const int lane = tid & 63, w = tid >> 6;        // w = token-subtile 0..3
    const int quad = lane >> 4, l16 = lane & 15;
    const int c0 = blockIdx.x * 128;                // token tile
    const int r0 = blockIdx.y * 64;                 // outcol tile
    floatx4 acc[4][2];
#pragma unroll
    for (int i = 0; i < 4; ++i)
#pragma unroll
        for (int j = 0; j < 2; ++j) acc[i][j] = (floatx4){0.f, 0.f, 0.f, 0.f};
    const int srow = tid >> 2;                      // 0..63
    const int sgx  = ((tid & 3) ^ ((srow >> 1) & 3)) * 8;
    const short* Ag = wt + (size_t)(r0 + srow) * 1024 + sgx;
    const short* Bg = xb + (size_t)(c0 + srow) * 1024 + sgx;
    const int fsw = (l16 >> 1) & 3;
    for (int kk = 0; kk < 1024; kk += 32) {
        __syncthreads();
        GLDS16(Ag + kk,                     As + tid * 8);
        GLDS16(Bg + kk,                     Bs + tid * 8);
        GLDS16(Bg + (size_t)64 * 1024 + kk, Bs + 2048 + tid * 8);
        __syncthreads();
        short8 af[4], bf[2];
#pragma unroll
        for (int mt = 0; mt < 4; ++mt)
            af[mt] = *(const short8*)&As[(mt * 16 + l16) * 32 + (quad ^ fsw) * 8];
#pragma unroll
        for (int nt = 0; nt < 2; ++nt)
            bf[nt] = *(const short8*)&Bs[(w * 32 + nt * 16 + l16) * 32 + (quad ^ fsw) * 8];
#pragma unroll
        for (int mt = 0; mt < 4; ++mt)
#pragma unroll
            for (int nt = 0; nt < 2; ++nt)
                acc[mt][nt] = __builtin_amdgcn_mfma_f32_16x16x32_bf16(
                    af[mt], bf[nt], acc[mt][nt], 0, 0, 0);
    }
#pragma unroll
    for (int mt = 0; mt < 4; ++mt) {
        int oc0 = r0 + mt * 16 + quad * 4;          // 4 consecutive out-cols
        int head = oc0 / 192;
        int t = (oc0 - head * 192) >> 6;            // 0=q 1=k 2=v (block-uniform)
        int d0 = oc0 & 63;
        float4 bv = *(const float4*)(bias + oc0);
#pragma unroll
        for (int nt = 0; nt < 2; ++nt) {
            int tok = c0 + w * 32 + nt * 16 + l16;
            int bh = (tok >> 11) * NH + head;
            float v0 = acc[mt][nt][0] + bv.x, v1 = acc[mt][nt][1] + bv.y;
            float v2 = acc[mt][nt][2] + bv.z, v3 = acc[mt][nt][3] + bv.w;
            if (t == 2) {
                // V -> vfb LDS-image: key n; h = nt (16-half within 32-chunk)
                int n  = tok & (SEQ - 1);
                int h  = nt;
                int qv = l16 >> 2, r = l16 & 3;
                int j  = h * 4 + r;                 // frag element
                size_t vb = (size_t)bh * 131072 + (size_t)(n >> 7) * 8192
                          + (size_t)((n >> 5) & 3) * 2048 + (size_t)d0 * 32 + j;
                _Float16 vv[4] = { (_Float16)v0, (_Float16)v1,
                                   (_Float16)v2, (_Float16)v3 };
#pragma unroll
                for (int jj = 0; jj < 4; ++jj) {
                    int cset = qv ^ (((d0 + jj) >> 1) & 3);
                    vfb[vb + jj * 32 + cset * 8] = vv[jj];
                }
            } else {
                size_t base = ((size_t)bh * SEQ + (tok & (SEQ - 1))) * 64 + d0;
                if (t == 0) {
                    short4v o = { f2bf(v0 * QSCALE), f2bf(v1 * QSCALE),
                                  f2bf(v2 * QSCALE), f2bf(v3 * QSCALE) };
                    *(short4v*)(qb + base) = o;
                } else {
                    short4v o = { f2bf(v0), f2bf(v1), f2bf(v2), f2bf(v3) };
                    *(short4v*)(kb + base) = o;
                }
            }
        }
    }
}

// ---------------------------------------------------------------------------
// Stage 3: out^T = W_out^T @ O^T (+b). 256 threads, tile M=64 x N=128,
// BK=32 -> grid (32,16) = 512 blocks = 2 blocks/CU.
// ---------------------------------------------------------------------------
__global__ __launch_bounds__(256) void out_gemm_kernel(
    const short* __restrict__ wt, const short* __restrict__ ab,
    const float* __restrict__ bias, float* __restrict__ out)
{
    __shared__ short As[64 * 32];     // 4 KB
    __shared__ short Bs[128 * 32];    // 8 KB
    const int tid  = threadIdx.x;
    const int lane = tid & 63, w = tid >> 6;        // w = N-subtile 0..3
    const int quad = lane >> 4, l16 = lane & 15;
    const int c0 = blockIdx.x * 128;                // token tile
    const int r0 = blockIdx.y * 64;                 // outcol tile
    floatx4 acc[4][2];
#pragma unroll
    for (int i = 0; i < 4; ++i)
#pragma unroll
        for (int j = 0; j < 2; ++j) acc[i][j] = (floatx4){0.f, 0.f, 0.f, 0.f};
    const int srow = tid >> 2;                      // 0..63
    const int sgx  = ((tid & 3) ^ ((srow >> 1) & 3)) * 8;
    const short* Ag = wt + (size_t)(r0 + srow) * 1024 + sgx;
    const short* Bg = ab + (size_t)(c0 + srow) * 1024 + sgx;
    const int fsw = (l16 >> 1) & 3;
    for (int kk = 0; kk < 1024; kk += 32) {
        __syncthreads();
        GLDS16(Ag + kk,                   As + tid * 8);
        GLDS16(Bg + kk,                   Bs + tid * 8);
        GLDS16(Bg + (size_t)64 * 1024 + kk, Bs + 2048 + tid * 8);
        __syncthreads();
        short8 af[4], bf[2];
#pragma unroll
        for (int mt = 0; mt < 4; ++mt)
            af[mt] = *(const short8*)&As[(mt * 16 + l16) * 32 + (quad ^ fsw) * 8];
#pragma unroll
        for (int nt = 0; nt < 2; ++nt)
            bf[nt] = *(const short8*)&Bs[(w * 32 + nt * 16 + l16) * 32 + (quad ^ fsw) * 8];
#pragma unroll
        for (int mt = 0; mt < 4; ++mt)
#pragma unroll
            for (int nt = 0; nt < 2; ++nt)
                acc[mt][nt] = __builtin_amdgcn_mfma_f32_16x16x32_bf16(
                    af[mt], bf[nt], acc[mt][nt], 0, 0, 0);
    }
#pragma unroll
    for (int mt = 0; mt < 4; ++mt) {
        int oc0 = r0 + mt * 16 + quad * 4;
        float4 bv = *(const float4*)(bias + oc0);
#pragma unroll
        for (int nt = 0; nt < 2; ++nt) {
            int tok = c0 + w * 32 + nt * 16 + l16;
            float4 o = { acc[mt][nt][0] + bv.x, acc[mt][nt][1] + bv.y,
                         acc[mt][nt][2] + bv.z, acc[mt][nt][3] + bv.w };
            *(float4*)(out + (size_t)tok * 1024 + oc0) = o;
        }
    }
}

// ---------------------------------------------------------------------------
// Stage 2: attention (unchanged round-11). 256 thr = 4 waves, each owning
// 32 queries of the block's 128-query range; every wave processes the full
// 128-key tile (4 u-blocks). Wave-local normalize+store epilogue.
// XCD-clustered: bh = (lb&7) + ((lb>>3)&3)*8 ; q0 = (lb>>5)*128.
// ---------------------------------------------------------------------------
__global__ __launch_bounds__(256, 2) void attn_kernel(
    const short* __restrict__ qb, const short* __restrict__ kb,
    const _Float16* __restrict__ vfb, short* __restrict__ ob)
{
    __shared__ short    Ks[128 * 64];    // 16 KB
    __shared__ _Float16 Vts[64 * 128];   // 16 KB, blocked [u][64][32]
    const int tid  = threadIdx.x;
    const int lane = tid & 63, w = tid >> 6;
    const int quad = lane >> 4, l16 = lane & 15;
    const int lb = blockIdx.x;
    const int bh = (lb & 7) + (((lb >> 3) & 3) << 3);  // XCD-clustered
    const int q0 = (lb >> 5) * 128;

    // Q fragments (B-frag of S^T): 2 q-tiles x 2 k-chunks, wave-owned queries
    short8 aq[2][2];
#pragma unroll
    for (int qf = 0; qf < 2; ++qf) {
        const short* qp = qb + ((size_t)bh * SEQ + q0 + w * 32 + qf * 16 + l16) * 64 + quad * 8;
        aq[qf][0] = *(const short8*)(qp);
        aq[qf][1] = *(const short8*)(qp + 32);
    }

    // GLDS source addresses (256 threads; 4 insts each for K and V)
    const int krow = tid >> 3, kg = tid & 7;   // K rows 0..31 (+32/64/96)
    const short* kgp = kb + ((size_t)bh * SEQ + krow) * 64 + (kg ^ (krow & 7)) * 8;
    const short* vgp = (const short*)(vfb + (size_t)bh * 131072) + tid * 8;  // linear image

    floatx4 o_acc[4][2];
#pragma unroll
    for (int dt = 0; dt < 4; ++dt)
#pragma unroll
        for (int qf = 0; qf < 2; ++qf) o_acc[dt][qf] = (floatx4){0.f, 0.f, 0.f, 0.f};
    float lw[2] = {0.f, 0.f};

    for (int k0 = 0; k0 < SEQ; k0 += 128) {
        __syncthreads();                       // prior iteration's reads done
        const short* kc_p = kgp + (size_t)k0 * 64;
        GLDS16(kc_p,        Ks + tid * 8);
        GLDS16(kc_p + 2048, Ks + 2048 + tid * 8);
        GLDS16(kc_p + 4096, Ks + 4096 + tid * 8);
        GLDS16(kc_p + 6144, Ks + 6144 + tid * 8);
        const short* vc_p = vgp + (size_t)k0 * 64;   // 64 halves per key
        GLDS16(vc_p,        (short*)Vts + tid * 8);
        GLDS16(vc_p + 2048, (short*)Vts + 2048 + tid * 8);
        GLDS16(vc_p + 4096, (short*)Vts + 4096 + tid * 8);
        GLDS16(vc_p + 6144, (short*)Vts + 6144 + tid * 8);
        __syncthreads();                       // staged (vmcnt drained)

#pragma unroll
        for (int u = 0; u < 4; ++u) {          // all 4 u-blocks per wave
            half8 av8[4];
#pragma unroll
            for (int dt = 0; dt < 4; ++dt) {
                union { short8 s; half8 h; } vv;
                vv.s = *(const short8*)((const short*)Vts + u * 2048
                        + (dt * 16 + l16) * 32 + (quad ^ ((l16 >> 1) & 3)) * 8);
                av8[dt] = vv.h;
            }
            floatx4 sacc[2][2];                // [h][qf]
#pragma unroll
            for (int h = 0; h < 2; ++h) {      // 16-key chunk within u-block
                const short* krp = &Ks[(u * 32 + h * 16 + l16) * 64];
                short8 ak0 = *(const short8*)(krp + ((0 + quad) ^ (l16 & 7)) * 8);
                short8 ak1 = *(const short8*)(krp + ((4 + quad) ^ (l16 & 7)) * 8);
                __builtin_amdgcn_s_setprio(1);
#pragma unroll
                for (int qf = 0; qf < 2; ++qf) {
                    floatx4 z = (floatx4){0.f, 0.f, 0.f, 0.f};
                    z = __builtin_amdgcn_mfma_f32_16x16x32_bf16(ak0, aq[qf][0], z, 0, 0, 0);
                    sacc[h][qf] = __builtin_amdgcn_mfma_f32_16x16x32_bf16(ak1, aq[qf][1], z, 0, 0, 0);
                }
                __builtin_amdgcn_s_setprio(0);
            }
            half8 pf8[2];
#pragma unroll
            for (int qf = 0; qf < 2; ++qf) {
                float p0 = fast_exp2(sacc[0][qf][0]);
                float p1 = fast_exp2(sacc[0][qf][1]);
                float p2 = fast_exp2(sacc[0][qf][2]);
                float p3 = fast_exp2(sacc[0][qf][3]);
                float p4 = fast_exp2(sacc[1][qf][0]);
                float p5 = fast_exp2(sacc[1][qf][1]);
                float p6 = fast_exp2(sacc[1][qf][2]);
                float p7 = fast_exp2(sacc[1][qf][3]);
                lw[qf] += ((p0 + p1) + (p2 + p3)) + ((p4 + p5) + (p6 + p7));
                half2v a = cvt_pk(p0, p1), b = cvt_pk(p2, p3);
                half2v c = cvt_pk(p4, p5), d = cvt_pk(p6, p7);
                pf8[qf] = (half8){a.x, a.y, b.x, b.y, c.x, c.y, d.x, d.y};
            }
            __builtin_amdgcn_s_setprio(1);
#pragma unroll
            for (int dt = 0; dt < 4; ++dt)
#pragma unroll
                for (int qf = 0; qf < 2; ++qf)
                    o_acc[dt][qf] = __builtin_amdgcn_mfma_f32_16x16x32_f16(
                        av8[dt], pf8[qf], o_acc[dt][qf], 0, 0, 0);
            __builtin_amdgcn_s_setprio(0);
        }
    }

    // l: reduce across quads (each lane summed only its quad's key slice)
    float inv[2];
#pragma unroll
    for (int qf = 0; qf < 2; ++qf) {
        lw[qf] += __shfl_xor(lw[qf], 16);
        lw[qf] += __shfl_xor(lw[qf], 32);
        inv[qf] = 1.0f / lw[qf];
    }

    // wave-local normalize + store (no cross-wave reduction needed)
    const int b = bh >> 4, h = bh & 15;
#pragma unroll
    for (int dt = 0; dt < 4; ++dt)
#pragma unroll
        for (int qf = 0; qf < 2; ++qf) {
            int tok = b * SEQ + q0 + w * 32 + qf * 16 + l16;
            floatx4 o = o_acc[dt][qf];
            short4v o4 = { f2bf(o[0] * inv[qf]), f2bf(o[1] * inv[qf]),
                           f2bf(o[2] * inv[qf]), f2bf(o[3] * inv[qf]) };
            *(short4v*)(ob + (size_t)tok * 1024 + h * 64 + dt * 16 + quad * 4) = o4;
        }
}

extern "C" void kernel_launch(void* const* d_in, const int* in_sizes, int n_in,
                              void* d_out, int out_size, void* d_ws, size_t ws_size,
                              hipStream_t stream) {
    const float* x     = (const float*)d_in[0];   // [2,2048,1024]
    const float* W_qkv = (const float*)d_in[1];   // [1024,3072]
    const float* b_qkv = (const float*)d_in[2];   // [3072]
    const float* W_out = (const float*)d_in[3];   // [1024,1024]
    const float* b_out = (const float*)d_in[4];   // [1024]
    float* out = (float*)d_out;                   // [2,2048,1024] fp32

    short* xb      = (short*)d_ws;                             // 8 MB
    short* wqkvt   = xb    + (size_t)4096 * 1024;              // 6 MB [3072][1024]
    short* woutt   = wqkvt + (size_t)3072 * 1024;              // 2 MB [1024][1024]
    short* qb      = woutt + (size_t)1024 * 1024;              // 8 MB [32][2048][64]
    short* kb      = qb    + (size_t)32 * SEQ * 64;            // 8 MB
    _Float16* vfb  = (_Float16*)(kb + (size_t)32 * SEQ * 64);  // 8 MB LDS-image V
    short* ob      = (short*)(vfb + (size_t)32 * 64 * SEQ);    // 8 MB [4096][1024]

    prep_kernel<<<3072, 256, 0, stream>>>(x, xb, W_qkv, wqkvt, W_out, woutt);
    qkv_gemm_kernel<<<dim3(32, 48), 256, 0, stream>>>(wqkvt, xb, b_qkv, qb, kb, vfb);
    attn_kernel<<<512, 256, 0, stream>>>(qb, kb, vfb, ob);
    out_gemm_kernel<<<dim3(32, 16), 256, 0, stream>>>(woutt, ob, b_out, out);
}

// Round 13
// 172.072 us; speedup vs baseline: 1.0885x; 1.0885x over previous
//
#include <hip/hip_runtime.h>

// bf16/f16 MFMA pipeline. E=1024, H=16, HD=64, B=2, N=2048.
// attn: 256-thr blocks own 128 QUERIES x all keys; 4 waves split by query
// (32 q each), each wave processes the full 128-key staged tile (4 u-blocks).
// Grid 512, XCD-clustered (lb%8 = XCD): each XCD owns 4 bh (2MB K/V in L2).
// K GLDS-staged (XOR-swizzled); V GLDS-staged LINEARLY from vfb (LDS image,
// swizzle pre-baked by the qkv epilogue).
// qkv: 128x128 BK=32 GEMM_CORE, grid (32,24) = 3 blocks/CU (proven round-8;
// round-12's M=64 retile REGRESSED: halves MFMA-per-barrier while staging
// only drops 4->3 GLDS -> worse arithmetic intensity per block).
// out_gemm: M=64 x N=128 BK=32, grid (32,16) = 2 blocks/CU (proven round-10).
// mfma_f32_16x16x32_bf16: A[m=l16][k=quad*8+j] ; B[k=quad*8+j][n=l16]
//                         C/D: D[row=quad*4+reg][col=l16]
// PV uses mfma_f32_16x16x32_f16 (K=32, full rate).

#define SEQ 2048
#define NH  16

typedef __attribute__((ext_vector_type(8))) short short8;
typedef __attribute__((ext_vector_type(4))) short short4v;
typedef __attribute__((ext_vector_type(4))) float floatx4;
typedef __attribute__((ext_vector_type(4))) _Float16 half4;
typedef __attribute__((ext_vector_type(8))) _Float16 half8;
typedef __attribute__((ext_vector_type(2))) _Float16 half2v;
typedef __attribute__((ext_vector_type(2))) __fp16 fp16x2;

// fold 1/sqrt(64) * log2(e) into Q; softmax runs in exp2 domain with m=0
#define QSCALE 0.1803368801111204f

__device__ __forceinline__ short f2bf(float f) {
    union { float f; unsigned u; } v; v.f = f;
    unsigned r = v.u + 0x7fffu + ((v.u >> 16) & 1u);   // RNE
    return (short)(r >> 16);
}

__device__ __forceinline__ float fast_exp2(float x) {
#if __has_builtin(__builtin_amdgcn_exp2f)
    return __builtin_amdgcn_exp2f(x);
#else
    return exp2f(x);
#endif
}

__device__ __forceinline__ half2v cvt_pk(float a, float b) {
#if __has_builtin(__builtin_amdgcn_cvt_pkrtz)
    union { fp16x2 i; half2v o; } u;
    u.i = __builtin_amdgcn_cvt_pkrtz(a, b);
    return u.o;
#else
    half2v r; r.x = (_Float16)a; r.y = (_Float16)b; return r;
#endif
}

#define GLDS16(gp, lp)                                                          \
    __builtin_amdgcn_global_load_lds(                                           \
        (const __attribute__((address_space(1))) unsigned int*)(gp),            \
        (__attribute__((address_space(3))) unsigned int*)(lp), 16, 0, 0)

// ---------------------------------------------------------------------------
// Fused prep: [0,2048) cast x fp32->bf16 ; [2048,2816) transpose W_qkv ;
// [2816,3072) transpose W_out. One launch instead of three.
// ---------------------------------------------------------------------------
__global__ __launch_bounds__(256) void prep_kernel(
    const float* __restrict__ x,  short* __restrict__ xb,
    const float* __restrict__ wq, short* __restrict__ wqkvt,
    const float* __restrict__ wo, short* __restrict__ woutt)
{
    const int tid = threadIdx.x;
    const int b = blockIdx.x;
    if (b < 2048) {
        int i = b * 256 + tid;
        const float4* in4 = (const float4*)x + (size_t)i * 2;
        float4 a = in4[0], c = in4[1];
        short8 o = { f2bf(a.x), f2bf(a.y), f2bf(a.z), f2bf(a.w),
                     f2bf(c.x), f2bf(c.y), f2bf(c.z), f2bf(c.w) };
        *((short8*)xb + i) = o;
        return;
    }
    __shared__ float T[64][65];
    const float* in; short* out; int R, C, c0, r0;
    if (b < 2816) {
        int t = b - 2048; in = wq; out = wqkvt; R = 1024; C = 3072;
        c0 = (t % 48) * 64; r0 = (t / 48) * 64;
    } else {
        int t = b - 2816; in = wo; out = woutt; R = 1024; C = 1024;
        c0 = (t & 15) * 64; r0 = (t >> 4) * 64;
    }
#pragma unroll
    for (int it = 0; it < 4; ++it) {
        int r = it * 16 + (tid >> 4), c = (tid & 15) * 4;
        float4 v = *(const float4*)(in + (size_t)(r0 + r) * C + c0 + c);
        T[c+0][r] = v.x; T[c+1][r] = v.y; T[c+2][r] = v.z; T[c+3][r] = v.w;
    }
    __syncthreads();
#pragma unroll
    for (int it = 0; it < 4; ++it) {
        int oc = it * 16 + (tid >> 4), k = (tid & 15) * 4;
        short4v o = { f2bf(T[oc][k]), f2bf(T[oc][k+1]), f2bf(T[oc][k+2]), f2bf(T[oc][k+3]) };
        *(short4v*)(out + (size_t)(c0 + oc) * R + r0 + k) = o;
    }
}

// ---------------------------------------------------------------------------
// MFMA GEMM core (256 thr): 128x128 tile, BK=32, GLDS w16, XOR-swizzled LDS.
// A rows = output-cols (weight^T), B rows = tokens (activations).
// ---------------------------------------------------------------------------
#define GEMM_CORE(A_PTR, B_PTR, LDA, LDB)                                        \
    __shared__ short As[128 * 32];                                               \
    __shared__ short Bs[128 * 32];                                               \
    const int tid  = threadIdx.x;                                                \
    const int lane = tid & 63, w = tid >> 6;                                     \
    const int quad = lane >> 4, l16 = lane & 15;                                 \
    const int wm = w >> 1, wn = w & 1;                                           \
    const int c0 = blockIdx.x * 128, r0 = blockIdx.y * 128;                      \
    floatx4 acc[4][4];                                                           \
    _Pragma("unroll")                                                            \
    for (int i = 0; i < 4; ++i)                                                  \
        _Pragma("unroll")                                                        \
        for (int j = 0; j < 4; ++j) acc[i][j] = (floatx4){0.f, 0.f, 0.f, 0.f};   \
    const int srow = tid >> 2;                                                   \
    const int sgx  = ((tid & 3) ^ ((srow >> 1) & 3)) * 8;                        \
    const short* Ag = (A_PTR) + (size_t)(r0 + srow) * (LDA) + sgx;               \
    const short* Bg = (B_PTR) + (size_t)(c0 + srow) * (LDB) + sgx;               \
    const int fsw = (l16 >> 1) & 3;                                              \
    for (int kk = 0; kk < 1024; kk += 32) {                                      \
        __syncthreads();                                                         \
        GLDS16(Ag + kk,                      As + tid * 8);                      \
        GLDS16(Ag + (size_t)64 * (LDA) + kk, As + 2048 + tid * 8);               \
        GLDS16(Bg + kk,                      Bs + tid * 8);                      \
        GLDS16(Bg + (size_t)64 * (LDB) + kk, Bs + 2048 + tid * 8);               \
        __syncthreads();                                                         \
        short8 af[4], bf[4];                                                     \
        _Pragma("unroll")                                                        \
        for (int mt = 0; mt < 4; ++mt)                                           \
            af[mt] = *(const short8*)&As[(wm * 64 + mt * 16 + l16) * 32 + (quad ^ fsw) * 8]; \
        _Pragma("unroll")                                                        \
        for (int nt = 0; nt < 4; ++nt)                                           \
            bf[nt] = *(const short8*)&Bs[(wn * 64 + nt * 16 + l16) * 32 + (quad ^ fsw) * 8]; \
        _Pragma("unroll")                                                        \
        for (int mt = 0; mt < 4; ++mt)                                           \
            _Pragma("unroll")                                                    \
            for (int nt = 0; nt < 4; ++nt)                                       \
                acc[mt][nt] = __builtin_amdgcn_mfma_f32_16x16x32_bf16(           \
                    af[mt], bf[nt], acc[mt][nt], 0, 0, 0);                       \
    }

// ---------------------------------------------------------------------------
// Stage 1: qkv^T = W_qkv^T @ x^T (+b). 128x128 GEMM_CORE, grid (32,24).
// Q/K: short4v stores per 4 consecutive d. V: scattered 2B stores into the
// attn LDS-image layout (vfb).
// ---------------------------------------------------------------------------
__global__ __launch_bounds__(256) void qkv_gemm_kernel(
    const short* __restrict__ wt, const short* __restrict__ xb,
    const float* __restrict__ bias,
    short* __restrict__ qb, short* __restrict__ kb, _Float16* __restrict__ vfb)
{
    GEMM_CORE(wt, xb, 1024, 1024)
#pragma unroll
    for (int mt = 0; mt < 4; ++mt) {
        int oc0 = r0 + wm * 64 + mt * 16 + quad * 4;   // 4 consecutive out-cols
        int head = oc0 / 192;
        int t = (oc0 - head * 192) >> 6;               // 0=q 1=k 2=v
        int d0 = oc0 & 63;
        float4 bv = *(const float4*)(bias + oc0);
#pragma unroll
        for (int nt = 0; nt < 4; ++nt) {
            int tok = c0 + wn * 64 + nt * 16 + l16;
            int bh = (tok >> 11) * NH + head;
            float v0 = acc[mt][nt][0] + bv.x, v1 = acc[mt][nt][1] + bv.y;
            float v2 = acc[mt][nt][2] + bv.z, v3 = acc[mt][nt][3] + bv.w;
            if (t == 2) {
                // V -> vfb LDS-image: key n, chunk c = n&31 = (nt&1)*16 + l16
                int n  = tok & (SEQ - 1);
                int h  = nt & 1;               // c>>4
                int qv = l16 >> 2, r = l16 & 3;
                int j  = h * 4 + r;            // frag element
                size_t vb = (size_t)bh * 131072 + (size_t)(n >> 7) * 8192
                          + (size_t)((n >> 5) & 3) * 2048 + (size_t)d0 * 32 + j;
                _Float16 vv[4] = { (_Float16)v0, (_Float16)v1,
                                   (_Float16)v2, (_Float16)v3 };
#pragma unroll
                for (int jj = 0; jj < 4; ++jj) {
                    int cset = qv ^ (((d0 + jj) >> 1) & 3);
                    vfb[vb + jj * 32 + cset * 8] = vv[jj];
                }
            } else {
                size_t base = ((size_t)bh * SEQ + (tok & (SEQ - 1))) * 64 + d0;
                if (t == 0) {
                    short4v o = { f2bf(v0 * QSCALE), f2bf(v1 * QSCALE),
                                  f2bf(v2 * QSCALE), f2bf(v3 * QSCALE) };
                    *(short4v*)(qb + base) = o;
                } else {
                    short4v o = { f2bf(v0), f2bf(v1), f2bf(v2), f2bf(v3) };
                    *(short4v*)(kb + base) = o;
                }
            }
        }
    }
}

// ---------------------------------------------------------------------------
// Stage 3: out^T = W_out^T @ O^T (+b). 256 threads, tile M=64 x N=128,
// BK=32 -> grid (32,16) = 512 blocks = 2 blocks/CU.
// ---------------------------------------------------------------------------
__global__ __launch_bounds__(256) void out_gemm_kernel(
    const short* __restrict__ wt, const short* __restrict__ ab,
    const float* __restrict__ bias, float* __restrict__ out)
{
    __shared__ short As[64 * 32];     // 4 KB
    __shared__ short Bs[128 * 32];    // 8 KB
    const int tid  = threadIdx.x;
    const int lane = tid & 63, w = tid >> 6;        // w = N-subtile 0..3
    const int quad = lane >> 4, l16 = lane & 15;
    const int c0 = blockIdx.x * 128;                // token tile
    const int r0 = blockIdx.y * 64;                 // outcol tile
    floatx4 acc[4][2];
#pragma unroll
    for (int i = 0; i < 4; ++i)
#pragma unroll
        for (int j = 0; j < 2; ++j) acc[i][j] = (floatx4){0.f, 0.f, 0.f, 0.f};
    const int srow = tid >> 2;                      // 0..63
    const int sgx  = ((tid & 3) ^ ((srow >> 1) & 3)) * 8;
    const short* Ag = wt + (size_t)(r0 + srow) * 1024 + sgx;
    const short* Bg = ab + (size_t)(c0 + srow) * 1024 + sgx;
    const int fsw = (l16 >> 1) & 3;
    for (int kk = 0; kk < 1024; kk += 32) {
        __syncthreads();
        GLDS16(Ag + kk,                   As + tid * 8);
        GLDS16(Bg + kk,                   Bs + tid * 8);
        GLDS16(Bg + (size_t)64 * 1024 + kk, Bs + 2048 + tid * 8);
        __syncthreads();
        short8 af[4], bf[2];
#pragma unroll
        for (int mt = 0; mt < 4; ++mt)
            af[mt] = *(const short8*)&As[(mt * 16 + l16) * 32 + (quad ^ fsw) * 8];
#pragma unroll
        for (int nt = 0; nt < 2; ++nt)
            bf[nt] = *(const short8*)&Bs[(w * 32 + nt * 16 + l16) * 32 + (quad ^ fsw) * 8];
#pragma unroll
        for (int mt = 0; mt < 4; ++mt)
#pragma unroll
            for (int nt = 0; nt < 2; ++nt)
                acc[mt][nt] = __builtin_amdgcn_mfma_f32_16x16x32_bf16(
                    af[mt], bf[nt], acc[mt][nt], 0, 0, 0);
    }
#pragma unroll
    for (int mt = 0; mt < 4; ++mt) {
        int oc0 = r0 + mt * 16 + quad * 4;
        float4 bv = *(const float4*)(bias + oc0);
#pragma unroll
        for (int nt = 0; nt < 2; ++nt) {
            int tok = c0 + w * 32 + nt * 16 + l16;
            float4 o = { acc[mt][nt][0] + bv.x, acc[mt][nt][1] + bv.y,
                         acc[mt][nt][2] + bv.z, acc[mt][nt][3] + bv.w };
            *(float4*)(out + (size_t)tok * 1024 + oc0) = o;
        }
    }
}

// ---------------------------------------------------------------------------
// Stage 2: attention (round-11). 256 thr = 4 waves, each owning 32 queries
// of the block's 128-query range; every wave processes the full 128-key tile
// (4 u-blocks). Wave-local normalize+store epilogue. Grid 512.
// XCD-clustered: bh = (lb&7) + ((lb>>3)&3)*8 ; q0 = (lb>>5)*128.
// ---------------------------------------------------------------------------
__global__ __launch_bounds__(256, 2) void attn_kernel(
    const short* __restrict__ qb, const short* __restrict__ kb,
    const _Float16* __restrict__ vfb, short* __restrict__ ob)
{
    __shared__ short    Ks[128 * 64];    // 16 KB
    __shared__ _Float16 Vts[64 * 128];   // 16 KB, blocked [u][64][32]
    const int tid  = threadIdx.x;
    const int lane = tid & 63, w = tid >> 6;
    const int quad = lane >> 4, l16 = lane & 15;
    const int lb = blockIdx.x;
    const int bh = (lb & 7) + (((lb >> 3) & 3) << 3);  // XCD-clustered
    const int q0 = (lb >> 5) * 128;

    // Q fragments (B-frag of S^T): 2 q-tiles x 2 k-chunks, wave-owned queries
    short8 aq[2][2];
#pragma unroll
    for (int qf = 0; qf < 2; ++qf) {
        const short* qp = qb + ((size_t)bh * SEQ + q0 + w * 32 + qf * 16 + l16) * 64 + quad * 8;
        aq[qf][0] = *(const short8*)(qp);
        aq[qf][1] = *(const short8*)(qp + 32);
    }

    // GLDS source addresses (256 threads; 4 insts each for K and V)
    const int krow = tid >> 3, kg = tid & 7;   // K rows 0..31 (+32/64/96)
    const short* kgp = kb + ((size_t)bh * SEQ + krow) * 64 + (kg ^ (krow & 7)) * 8;
    const short* vgp = (const short*)(vfb + (size_t)bh * 131072) + tid * 8;  // linear image

    floatx4 o_acc[4][2];
#pragma unroll
    for (int dt = 0; dt < 4; ++dt)
#pragma unroll
        for (int qf = 0; qf < 2; ++qf) o_acc[dt][qf] = (floatx4){0.f, 0.f, 0.f, 0.f};
    float lw[2] = {0.f, 0.f};

    for (int k0 = 0; k0 < SEQ; k0 += 128) {
        __syncthreads();                       // prior iteration's reads done
        const short* kc_p = kgp + (size_t)k0 * 64;
        GLDS16(kc_p,        Ks + tid * 8);
        GLDS16(kc_p + 2048, Ks + 2048 + tid * 8);
        GLDS16(kc_p + 4096, Ks + 4096 + tid * 8);
        GLDS16(kc_p + 6144, Ks + 6144 + tid * 8);
        const short* vc_p = vgp + (size_t)k0 * 64;   // 64 halves per key
        GLDS16(vc_p,        (short*)Vts + tid * 8);
        GLDS16(vc_p + 2048, (short*)Vts + 2048 + tid * 8);
        GLDS16(vc_p + 4096, (short*)Vts + 4096 + tid * 8);
        GLDS16(vc_p + 6144, (short*)Vts + 6144 + tid * 8);
        __syncthreads();                       // staged (vmcnt drained)

#pragma unroll
        for (int u = 0; u < 4; ++u) {          // all 4 u-blocks per wave
            half8 av8[4];
#pragma unroll
            for (int dt = 0; dt < 4; ++dt) {
                union { short8 s; half8 h; } vv;
                vv.s = *(const short8*)((const short*)Vts + u * 2048
                        + (dt * 16 + l16) * 32 + (quad ^ ((l16 >> 1) & 3)) * 8);
                av8[dt] = vv.h;
            }
            floatx4 sacc[2][2];                // [h][qf]
#pragma unroll
            for (int h = 0; h < 2; ++h) {      // 16-key chunk within u-block
                const short* krp = &Ks[(u * 32 + h * 16 + l16) * 64];
                short8 ak0 = *(const short8*)(krp + ((0 + quad) ^ (l16 & 7)) * 8);
                short8 ak1 = *(const short8*)(krp + ((4 + quad) ^ (l16 & 7)) * 8);
                __builtin_amdgcn_s_setprio(1);
#pragma unroll
                for (int qf = 0; qf < 2; ++qf) {
                    floatx4 z = (floatx4){0.f, 0.f, 0.f, 0.f};
                    z = __builtin_amdgcn_mfma_f32_16x16x32_bf16(ak0, aq[qf][0], z, 0, 0, 0);
                    sacc[h][qf] = __builtin_amdgcn_mfma_f32_16x16x32_bf16(ak1, aq[qf][1], z, 0, 0, 0);
                }
                __builtin_amdgcn_s_setprio(0);
            }
            half8 pf8[2];
#pragma unroll
            for (int qf = 0; qf < 2; ++qf) {
                float p0 = fast_exp2(sacc[0][qf][0]);
                float p1 = fast_exp2(sacc[0][qf][1]);
                float p2 = fast_exp2(sacc[0][qf][2]);
                float p3 = fast_exp2(sacc[0][qf][3]);
                float p4 = fast_exp2(sacc[1][qf][0]);
                float p5 = fast_exp2(sacc[1][qf][1]);
                float p6 = fast_exp2(sacc[1][qf][2]);
                float p7 = fast_exp2(sacc[1][qf][3]);
                lw[qf] += ((p0 + p1) + (p2 + p3)) + ((p4 + p5) + (p6 + p7));
                half2v a = cvt_pk(p0, p1), b = cvt_pk(p2, p3);
                half2v c = cvt_pk(p4, p5), d = cvt_pk(p6, p7);
                pf8[qf] = (half8){a.x, a.y, b.x, b.y, c.x, c.y, d.x, d.y};
            }
            __builtin_amdgcn_s_setprio(1);
#pragma unroll
            for (int dt = 0; dt < 4; ++dt)
#pragma unroll
                for (int qf = 0; qf < 2; ++qf)
                    o_acc[dt][qf] = __builtin_amdgcn_mfma_f32_16x16x32_f16(
                        av8[dt], pf8[qf], o_acc[dt][qf], 0, 0, 0);
            __builtin_amdgcn_s_setprio(0);
        }
    }

    // l: reduce across quads (each lane summed only its quad's key slice)
    float inv[2];
#pragma unroll
    for (int qf = 0; qf < 2; ++qf) {
        lw[qf] += __shfl_xor(lw[qf], 16);
        lw[qf] += __shfl_xor(lw[qf], 32);
        inv[qf] = 1.0f / lw[qf];
    }

    // wave-local normalize + store (no cross-wave reduction needed)
    const int b = bh >> 4, h = bh & 15;
#pragma unroll
    for (int dt = 0; dt < 4; ++dt)
#pragma unroll
        for (int qf = 0; qf < 2; ++qf) {
            int tok = b * SEQ + q0 + w * 32 + qf * 16 + l16;
            floatx4 o = o_acc[dt][qf];
            short4v o4 = { f2bf(o[0] * inv[qf]), f2bf(o[1] * inv[qf]),
                           f2bf(o[2] * inv[qf]), f2bf(o[3] * inv[qf]) };
            *(short4v*)(ob + (size_t)tok * 1024 + h * 64 + dt * 16 + quad * 4) = o4;
        }
}

extern "C" void kernel_launch(void* const* d_in, const int* in_sizes, int n_in,
                              void* d_out, int out_size, void* d_ws, size_t ws_size,
                              hipStream_t stream) {
    const float* x     = (const float*)d_in[0];   // [2,2048,1024]
    const float* W_qkv = (const float*)d_in[1];   // [1024,3072]
    const float* b_qkv = (const float*)d_in[2];   // [3072]
    const float* W_out = (const float*)d_in[3];   // [1024,1024]
    const float* b_out = (const float*)d_in[4];   // [1024]
    float* out = (float*)d_out;                   // [2,2048,1024] fp32

    short* xb      = (short*)d_ws;                             // 8 MB
    short* wqkvt   = xb    + (size_t)4096 * 1024;              // 6 MB [3072][1024]
    short* woutt   = wqkvt + (size_t)3072 * 1024;              // 2 MB [1024][1024]
    short* qb      = woutt + (size_t)1024 * 1024;              // 8 MB [32][2048][64]
    short* kb      = qb    + (size_t)32 * SEQ * 64;            // 8 MB
    _Float16* vfb  = (_Float16*)(kb + (size_t)32 * SEQ * 64);  // 8 MB LDS-image V
    short* ob      = (short*)(vfb + (size_t)32 * 64 * SEQ);    // 8 MB [4096][1024]

    prep_kernel<<<3072, 256, 0, stream>>>(x, xb, W_qkv, wqkvt, W_out, woutt);
    qkv_gemm_kernel<<<dim3(32, 24), 256, 0, stream>>>(wqkvt, xb, b_qkv, qb, kb, vfb);
    attn_kernel<<<512, 256, 0, stream>>>(qb, kb, vfb, ob);
    out_gemm_kernel<<<dim3(32, 16), 256, 0, stream>>>(woutt, ob, b_out, out);
}